// Round 1
// baseline (142.259 us; speedup 1.0000x reference)
//
#include <hip/hip_runtime.h>

// out[i] = F[inds[i]] for i in [0, 2*CARD) = [0, 100)
// F: 30M float32, inds: 100 int32, out: 100 float32.
// One tiny block; entirely launch-overhead bound.

__global__ void SimplexTreeModel_63642825392498_kernel(const float* __restrict__ F,
                                                       const int* __restrict__ inds,
                                                       float* __restrict__ out,
                                                       int n) {
    int i = blockIdx.x * blockDim.x + threadIdx.x;
    if (i < n) {
        out[i] = F[inds[i]];
    }
}

extern "C" void kernel_launch(void* const* d_in, const int* in_sizes, int n_in,
                              void* d_out, int out_size, void* d_ws, size_t ws_size,
                              hipStream_t stream) {
    const float* F    = (const float*)d_in[0];
    const int*   inds = (const int*)d_in[1];
    float*       out  = (float*)d_out;
    int n = in_sizes[1];  // 2*CARD = 100 gather indices == out_size

    SimplexTreeModel_63642825392498_kernel<<<1, 128, 0, stream>>>(F, inds, out, n);
}